// Round 10
// baseline (373.550 us; speedup 1.0000x reference)
//
#include <hip/hip_runtime.h>

// ---------------------------------------------------------------------------
// Problem constants
// ---------------------------------------------------------------------------
#define N_PFAS 20000
#define N_GW   100000
#define N_SW   30000
#define E_PG   1600000
#define E_GP   640000
#define E_PS   480000
#define E_SP   320000
#define E_TOT  (E_PG + E_PS + E_GP + E_SP)
// Concatenated node-count layout: [pg: N_GW][ps: N_SW][gp: N_PFAS][sp: N_PFAS]
#define BASE_PG 0
#define BASE_PS (N_GW)
#define BASE_GP (N_GW + N_SW)
#define BASE_SP (N_GW + N_SW + N_PFAS)
#define NTOT    (N_GW + N_SW + 2 * N_PFAS)
// Bucketed permute: 256 nodes per bucket; fixed-capacity pair regions.
#define NB        ((NTOT + 255) / 256)       // 665
#define SEG_CAP   9216                       // max bucket ~8.5K (gp: 32/node)
#define BIN_EPT   12
#define BIN_EPB   (256 * BIN_EPT)            // 3072 edges/block
#define BIN_NBLK  ((E_TOT + BIN_EPB - 1) / BIN_EPB)   // 990
// MFMA transform tiles (64 rows each); one (tile, matrix) product per block.
#define T64_PF ((N_PFAS + 63) / 64)          // 313
#define T64_GW ((N_GW + 63) / 64)            // 1563
#define T64_SW ((N_SW + 63) / 64)            // 469
#define PROD_BLKS (3 * T64_PF + 2 * T64_GW + 2 * T64_SW)   // 5003
// Merged gather dispatch: seg blocks first (fattest), then gw/sw.
#define SEGP_BLKS (N_PFAS / 16)              // 1250 (1 node/group; gp+sp+finalize)
#define GW_BLKS   ((N_GW + 31) / 32)         // 3125 (2 rows/group)
#define SW_BLKS   ((N_SW + 31) / 32)         // 938
// LDS stride (f16 elems): 136 = 272B; X-stage and C-stage union per wave.
#define SSTR 136

// ---------------------------------------------------------------------------
// f16 helpers
// ---------------------------------------------------------------------------
typedef _Float16 h2_t  __attribute__((ext_vector_type(2)));
typedef _Float16 f16x4 __attribute__((ext_vector_type(4)));
typedef _Float16 f16x8 __attribute__((ext_vector_type(8)));
typedef float    f32x4 __attribute__((ext_vector_type(4)));
union HU { unsigned u; h2_t h; };
__device__ __forceinline__ h2_t u2h2(unsigned u) { HU x; x.u = u; return x.h; }

// ---------------------------------------------------------------------------
// 8-ILP f16 gather-sum over a CSR segment (8B/lane, 32 lanes/row):
// tl = sum of channels (4tx,4tx+1), th = (4tx+2,4tx+3).
// ---------------------------------------------------------------------------
__device__ __forceinline__ void gather_sum_f16(
    const unsigned short* __restrict__ bufT16, const int* __restrict__ perm,
    int lo, int hi, int tx, h2_t& tl, h2_t& th)
{
    h2_t hz; hz.x = (_Float16)0.f; hz.y = (_Float16)0.f;
    h2_t a0 = hz, a1 = hz, a2 = hz, a3 = hz, a4 = hz, a5 = hz, a6 = hz, a7 = hz;
    int i = lo;
    for (; i + 8 <= hi; i += 8) {
        uint2 v0 = *(const uint2*)(bufT16 + (size_t)perm[i + 0] * 128 + tx * 4);
        uint2 v1 = *(const uint2*)(bufT16 + (size_t)perm[i + 1] * 128 + tx * 4);
        uint2 v2 = *(const uint2*)(bufT16 + (size_t)perm[i + 2] * 128 + tx * 4);
        uint2 v3 = *(const uint2*)(bufT16 + (size_t)perm[i + 3] * 128 + tx * 4);
        uint2 v4 = *(const uint2*)(bufT16 + (size_t)perm[i + 4] * 128 + tx * 4);
        uint2 v5 = *(const uint2*)(bufT16 + (size_t)perm[i + 5] * 128 + tx * 4);
        uint2 v6 = *(const uint2*)(bufT16 + (size_t)perm[i + 6] * 128 + tx * 4);
        uint2 v7 = *(const uint2*)(bufT16 + (size_t)perm[i + 7] * 128 + tx * 4);
        a0 += u2h2(v0.x); a1 += u2h2(v0.y);
        a2 += u2h2(v1.x); a3 += u2h2(v1.y);
        a4 += u2h2(v2.x); a5 += u2h2(v2.y);
        a6 += u2h2(v3.x); a7 += u2h2(v3.y);
        a0 += u2h2(v4.x); a1 += u2h2(v4.y);
        a2 += u2h2(v5.x); a3 += u2h2(v5.y);
        a4 += u2h2(v6.x); a5 += u2h2(v6.y);
        a6 += u2h2(v7.x); a7 += u2h2(v7.y);
    }
    for (; i + 2 <= hi; i += 2) {
        uint2 v0 = *(const uint2*)(bufT16 + (size_t)perm[i + 0] * 128 + tx * 4);
        uint2 v1 = *(const uint2*)(bufT16 + (size_t)perm[i + 1] * 128 + tx * 4);
        a0 += u2h2(v0.x); a1 += u2h2(v0.y);
        a2 += u2h2(v1.x); a3 += u2h2(v1.y);
    }
    if (i < hi) {
        uint2 v0 = *(const uint2*)(bufT16 + (size_t)perm[i] * 128 + tx * 4);
        a0 += u2h2(v0.x); a1 += u2h2(v0.y);
    }
    tl = (a0 + a2) + (a4 + a6);
    th = (a1 + a3) + (a5 + a7);
}

// ---------------------------------------------------------------------------
// Weight prep (28 blocks = 7 matrices x 4 chunks): fragment-linear f16 WtF.
// Block 0 also zeroes gcursor and writes off_all[NTOT]. m==2 sums Wr_gp+Wr_sp.
// ---------------------------------------------------------------------------
__global__ __launch_bounds__(256) void prep_wt_kernel(
    const float* __restrict__ Wl_pg, const float* __restrict__ Wl_ps,
    const float* __restrict__ Wr_gp, const float* __restrict__ Wr_sp,
    const float* __restrict__ Wl_gp, const float* __restrict__ Wr_pg,
    const float* __restrict__ Wl_sp, const float* __restrict__ Wr_ps,
    _Float16* __restrict__ WtF_pg, _Float16* __restrict__ WtF_ps,
    _Float16* __restrict__ WtFR_pf,
    _Float16* __restrict__ WtF_gp, _Float16* __restrict__ WtFR_gw,
    _Float16* __restrict__ WtF_sp, _Float16* __restrict__ WtFR_sw,
    int* __restrict__ gcursor, int* __restrict__ off_all)
{
    const int m = blockIdx.x >> 2;
    const int chunk = blockIdx.x & 3;
    if (blockIdx.x == 0) {
        for (int i = threadIdx.x; i < NB; i += 256) gcursor[i] = 0;
        if (threadIdx.x == 0) off_all[NTOT] = E_TOT;
    }
    const float* A = nullptr; const float* B = nullptr; _Float16* O = nullptr;
    switch (m) {
        case 0: A = Wl_pg; O = WtF_pg;  break;
        case 1: A = Wl_ps; O = WtF_ps;  break;
        case 2: A = Wr_gp; B = Wr_sp; O = WtFR_pf; break;
        case 3: A = Wl_gp; O = WtF_gp;  break;
        case 4: A = Wr_pg; O = WtFR_gw; break;
        case 5: A = Wl_sp; O = WtF_sp;  break;
        default: A = Wr_ps; O = WtFR_sw; break;
    }
    for (int t = chunk * 512 + threadIdx.x; t < (chunk + 1) * 512; t += 256) {
        int lane = t & 63, g = t >> 6;      // g = ct*4+ks
        int ks = g & 3, ct = g >> 2;
        int nn = ct * 16 + (lane & 15);
        int k0 = ks * 32 + (lane >> 4) * 8;
        f16x8 v;
#pragma unroll
        for (int j = 0; j < 8; ++j) {
            float x = A[(k0 + j) * 128 + nn];
            if (B) x += B[(k0 + j) * 128 + nn];
            v[j] = (_Float16)x;
        }
        *(f16x8*)(O + (size_t)t * 8) = v;
    }
}

// ---------------------------------------------------------------------------
// MFMA with B from LDS: every B-frag is a conflict-free ds_read_b128 (lane L
// reads bytes 16L..16L+15 of a 1KB block) — zero global latency in the MFMA
// loop. C -> per-wave LDS stage (reuses the X region, wave-local ordering)
// -> f16x8 readback -> coalesced 16B/lane global stores.
// C layout (verified): col = lane&15, row = (lane>>4)*4 + reg.
// ---------------------------------------------------------------------------
__device__ __forceinline__ void mfma_lds_B16(
    const _Float16* sW, const f16x8* a, _Float16* sstage,
    int rbase, int n, int lane, _Float16* __restrict__ o16)
{
    f32x4 acc[8];
#pragma unroll
    for (int ct = 0; ct < 8; ++ct) acc[ct] = (f32x4){0.f, 0.f, 0.f, 0.f};
#pragma unroll
    for (int ct = 0; ct < 8; ++ct) {
        f16x8 b0 = *(const f16x8*)(sW + ((ct * 4 + 0) * 64 + lane) * 8);
        f16x8 b1 = *(const f16x8*)(sW + ((ct * 4 + 1) * 64 + lane) * 8);
        f16x8 b2 = *(const f16x8*)(sW + ((ct * 4 + 2) * 64 + lane) * 8);
        f16x8 b3 = *(const f16x8*)(sW + ((ct * 4 + 3) * 64 + lane) * 8);
        acc[ct] = __builtin_amdgcn_mfma_f32_16x16x32_f16(a[0], b0, acc[ct], 0, 0, 0);
        acc[ct] = __builtin_amdgcn_mfma_f32_16x16x32_f16(a[1], b1, acc[ct], 0, 0, 0);
        acc[ct] = __builtin_amdgcn_mfma_f32_16x16x32_f16(a[2], b2, acc[ct], 0, 0, 0);
        acc[ct] = __builtin_amdgcn_mfma_f32_16x16x32_f16(a[3], b3, acc[ct], 0, 0, 0);
    }

    const int rl = (lane >> 4) * 4;
    const int cb = lane & 15;
#pragma unroll
    for (int ct = 0; ct < 8; ++ct)
#pragma unroll
        for (int e = 0; e < 4; ++e)
            sstage[(rl + e) * SSTR + ct * 16 + cb] = (_Float16)acc[ct][e];

#pragma unroll
    for (int i = 0; i < 4; ++i) {
        int lr = i * 4 + (lane >> 4);
        int r = rbase + lr;
        if (r < n) {
            f16x8 v = *(const f16x8*)(sstage + lr * SSTR + cb * 8);
            *(f16x8*)(o16 + ((size_t)r << 7) + cb * 8) = v;
        }
    }
}

// f32-output variant (R_pf only, 313 blocks): scalar stores, no C-stage.
__device__ __forceinline__ void mfma_lds_B32(
    const _Float16* sW, const f16x8* a,
    int rbase, int n, int lane, float* __restrict__ o32)
{
    f32x4 acc[8];
#pragma unroll
    for (int ct = 0; ct < 8; ++ct) acc[ct] = (f32x4){0.f, 0.f, 0.f, 0.f};
#pragma unroll
    for (int ct = 0; ct < 8; ++ct) {
        f16x8 b0 = *(const f16x8*)(sW + ((ct * 4 + 0) * 64 + lane) * 8);
        f16x8 b1 = *(const f16x8*)(sW + ((ct * 4 + 1) * 64 + lane) * 8);
        f16x8 b2 = *(const f16x8*)(sW + ((ct * 4 + 2) * 64 + lane) * 8);
        f16x8 b3 = *(const f16x8*)(sW + ((ct * 4 + 3) * 64 + lane) * 8);
        acc[ct] = __builtin_amdgcn_mfma_f32_16x16x32_f16(a[0], b0, acc[ct], 0, 0, 0);
        acc[ct] = __builtin_amdgcn_mfma_f32_16x16x32_f16(a[1], b1, acc[ct], 0, 0, 0);
        acc[ct] = __builtin_amdgcn_mfma_f32_16x16x32_f16(a[2], b2, acc[ct], 0, 0, 0);
        acc[ct] = __builtin_amdgcn_mfma_f32_16x16x32_f16(a[3], b3, acc[ct], 0, 0, 0);
    }
    const int rowb = rbase + (lane >> 4) * 4;
    const int bcol = lane & 15;
#pragma unroll
    for (int ct = 0; ct < 8; ++ct) {
        const int col = ct * 16 + bcol;
#pragma unroll
        for (int e = 0; e < 4; ++e) {
            int r = rowb + e;
            if (r < n) o32[((size_t)r << 7) + col] = acc[ct][e];
        }
    }
}

// ---------------------------------------------------------------------------
// Mega dispatch: blocks [0,BIN_NBLK) bin edges into fixed-capacity bucket
// regions (gcursor atomics double as bucket counters); remaining blocks each
// compute ONE (tile, matrix) product with the 32KB weight staged in LDS —
// removes ALL global-load latency from the MFMA loop (the 90-101us wall of
// rounds 6-9 was B-frag L2 latency at low loads-in-flight).
// ---------------------------------------------------------------------------
__global__ __launch_bounds__(256, 2) void trans_bin_kernel(
    const float* __restrict__ x_pfas, const float* __restrict__ x_gw,
    const float* __restrict__ x_sw,
    const _Float16* __restrict__ WtF_pg, const _Float16* __restrict__ WtF_ps,
    const _Float16* __restrict__ WtFR_pf,
    const _Float16* __restrict__ WtF_gp, const _Float16* __restrict__ WtFR_gw,
    const _Float16* __restrict__ WtF_sp, const _Float16* __restrict__ WtFR_sw,
    _Float16* __restrict__ bufT_pg, _Float16* __restrict__ bufT_ps,
    float* __restrict__ R_pf,
    _Float16* __restrict__ bufT_gp, _Float16* __restrict__ R_gw,
    _Float16* __restrict__ bufT_sp, _Float16* __restrict__ R_sw,
    const int* __restrict__ s_pg, const int* __restrict__ d_pg,
    const int* __restrict__ s_ps, const int* __restrict__ d_ps,
    const int* __restrict__ s_gp, const int* __restrict__ d_gp,
    const int* __restrict__ s_sp, const int* __restrict__ d_sp,
    int* __restrict__ gcursor, unsigned* __restrict__ pairs)
{
    __shared__ char smem[32768 + 4 * 16 * SSTR * 2];   // 50176 B -> 3 blk/CU
    const int tid = threadIdx.x;

    if (blockIdx.x < BIN_NBLK) {
        int* hist = (int*)smem;            // NB
        int* chunkBase = hist + NB;        // NB
        for (int i = tid; i < NB; i += 256) hist[i] = 0;
        __syncthreads();

        const int base = blockIdx.x * BIN_EPB;
        int bkt[BIN_EPT], rnk[BIN_EPT];
        unsigned pk[BIN_EPT];
#pragma unroll
        for (int k = 0; k < BIN_EPT; ++k) {
            int e = base + k * 256 + tid;
            int idx = -1, src = 0;
            if (e < E_PG) { idx = BASE_PG + d_pg[e]; src = s_pg[e]; }
            else if (e < E_PG + E_PS) { int i2 = e - E_PG; idx = BASE_PS + d_ps[i2]; src = s_ps[i2]; }
            else if (e < E_PG + E_PS + E_GP) { int i2 = e - E_PG - E_PS; idx = BASE_GP + d_gp[i2]; src = s_gp[i2]; }
            else if (e < E_TOT) { int i2 = e - E_PG - E_PS - E_GP; idx = BASE_SP + d_sp[i2]; src = s_sp[i2]; }
            if (idx >= 0) {
                int b = idx >> 8;
                bkt[k] = b;
                rnk[k] = atomicAdd(&hist[b], 1);
                pk[k] = (unsigned)(idx & 255) | ((unsigned)src << 8);
            } else bkt[k] = -1;
        }
        __syncthreads();
        for (int i = tid; i < NB; i += 256) {
            int c = hist[i];
            chunkBase[i] = c ? atomicAdd(&gcursor[i], c) : 0;
        }
        __syncthreads();
#pragma unroll
        for (int k = 0; k < BIN_EPT; ++k) {
            if (bkt[k] >= 0) {
                int slot = chunkBase[bkt[k]] + rnk[k];
                if (slot < SEG_CAP)
                    pairs[(size_t)bkt[k] * SEG_CAP + slot] = pk[k];
            }
        }
        return;
    }

    // ---- product block decode: one (tile, matrix) per block ----
    const int b2 = blockIdx.x - BIN_NBLK;
    int tile, sub, n; const float* X;
    const _Float16* WtF; _Float16* o16 = nullptr; float* o32 = nullptr;
    if (b2 < 3 * T64_PF) {
        tile = b2 / 3; sub = b2 - tile * 3; X = x_pfas; n = N_PFAS;
        if (sub == 0)      { WtF = WtF_pg;  o16 = bufT_pg; }
        else if (sub == 1) { WtF = WtF_ps;  o16 = bufT_ps; }
        else               { WtF = WtFR_pf; o32 = R_pf; }
    } else if (b2 < 3 * T64_PF + 2 * T64_GW) {
        int t = b2 - 3 * T64_PF;
        tile = t >> 1; sub = t & 1; X = x_gw; n = N_GW;
        if (sub == 0) { WtF = WtF_gp;  o16 = bufT_gp; }
        else          { WtF = WtFR_gw; o16 = R_gw; }
    } else {
        int t = b2 - 3 * T64_PF - 2 * T64_GW;
        tile = t >> 1; sub = t & 1; X = x_sw; n = N_SW;
        if (sub == 0) { WtF = WtF_sp;  o16 = bufT_sp; }
        else          { WtF = WtFR_sw; o16 = R_sw; }
    }
    const int lane = tid & 63;
    const int w    = tid >> 6;
    const int rbase = tile * 64 + w * 16;
    _Float16* sW = (_Float16*)smem;                                   // 32 KB
    _Float16* sX = (_Float16*)(smem + 32768) + (size_t)w * 16 * SSTR; // per-wave

    // Cooperative W-stage: 32KB fragment-linear, fully coalesced (L2-hot).
    for (int t = tid; t < 2048; t += 256)
        *(f16x8*)(sW + t * 8) = *(const f16x8*)(WtF + (size_t)t * 8);

    // Per-wave coalesced X-stage with f32->f16 conversion in flight.
    const float* Xt = X + (size_t)rbase * 128;
    const int rows_left = n - rbase;
#pragma unroll
    for (int t = 0; t < 8; ++t) {
        int idx = t * 64 + lane;
        int rr = idx >> 5, c4 = idx & 31;
        float4 xv = make_float4(0.f, 0.f, 0.f, 0.f);
        if (rr < rows_left) xv = *(const float4*)(Xt + rr * 128 + c4 * 4);
        f16x4 v;
        v[0] = (_Float16)xv.x; v[1] = (_Float16)xv.y;
        v[2] = (_Float16)xv.z; v[3] = (_Float16)xv.w;
        *(f16x4*)(sX + rr * SSTR + c4 * 4) = v;
    }
    // a-frags from LDS (wave-local ordering; no barrier needed for X).
    f16x8 a[4];
#pragma unroll
    for (int ks = 0; ks < 4; ++ks)
        a[ks] = *(const f16x8*)(sX + (lane & 15) * SSTR + ks * 32 + (lane >> 4) * 8);
    __syncthreads();   // sW visible to all waves

    if (o32) mfma_lds_B32(sW, a, rbase, n, lane, o32);
    else     mfma_lds_B16(sW, a, sX, rbase, n, lane, o16);
}

// ---------------------------------------------------------------------------
// unbin: one 512-thread block per bucket. Computes its own bucket offset
// (prefix over gcursor, reduced in the sPerm space) — no scan dispatch.
// Per-node counts via LDS atomics, LDS scan -> off_all, scatter into LDS
// segment, stream out compacted.
// ---------------------------------------------------------------------------
__global__ __launch_bounds__(512) void unbin_kernel(
    const unsigned* __restrict__ pairs, const int* __restrict__ gcursor,
    int* __restrict__ off_all, int* __restrict__ perm_all)
{
    __shared__ int sPerm[SEG_CAP];
    __shared__ int cnt[256];
    __shared__ int sp[256];
    __shared__ int cur[256];
    const int b = blockIdx.x;
    const int nb0 = b << 8;
    const int nb1 = min(nb0 + 256, NTOT);
    const int tid = threadIdx.x;

    // bucket offset = prefix sum of gcursor[0..b-1] (reduce in sPerm space)
    int* red = sPerm;
    int part = 0;
    for (int i = tid; i < b; i += 512) part += gcursor[i];
    red[tid] = part;
    __syncthreads();
    for (int ofs = 256; ofs > 0; ofs >>= 1) {
        if (tid < ofs) red[tid] += red[tid + ofs];
        __syncthreads();
    }
    const int obase = red[0];
    int len = gcursor[b];
    if (len > SEG_CAP) len = SEG_CAP;
    const unsigned* reg = pairs + (size_t)b * SEG_CAP;

    if (tid < 256) cnt[tid] = 0;
    __syncthreads();                      // also fences red[0] reads vs sPerm reuse
    for (int i = tid; i < len; i += 512)
        atomicAdd(&cnt[reg[i] & 255u], 1);
    __syncthreads();
    int v = (tid < 256) ? cnt[tid] : 0;
    if (tid < 256) sp[tid] = v;
    __syncthreads();
    for (int ofs = 1; ofs < 256; ofs <<= 1) {
        int add = (tid < 256 && tid >= ofs) ? sp[tid - ofs] : 0;
        __syncthreads();
        if (tid < 256) sp[tid] += add;
        __syncthreads();
    }
    if (tid < 256) {
        int excl = sp[tid] - v;
        cur[tid] = excl;
        if (nb0 + tid < nb1) off_all[nb0 + tid] = obase + excl;
    }
    __syncthreads();

    for (int i = tid; i < len; i += 512) {
        unsigned p = reg[i];
        int pos = atomicAdd(&cur[p & 255u], 1);
        sPerm[pos] = (int)(p >> 8);
    }
    __syncthreads();
    for (int i = tid; i < len; i += 512)
        perm_all[obase + i] = sPerm[i];
}

// ---------------------------------------------------------------------------
// Merged gather dispatch: GEMM-free, LDS-free, barrier-free.
//  blocks [0, SEGP): pfas nodes — gp-gather + sp-gather + R_pf + biases +
//    relu -> h_pf directly.
//  blocks [SEGP, +GW+SW): gw/sw node pass, 32 nodes/block, 2 rows/group.
// ---------------------------------------------------------------------------
__global__ __launch_bounds__(512, 8) void gather_all_kernel(
    const _Float16* __restrict__ R_gw, const _Float16* __restrict__ R_sw,
    const float* __restrict__ bl_pg, const float* __restrict__ bl_ps,
    const unsigned short* __restrict__ bufT_pg,
    const unsigned short* __restrict__ bufT_ps,
    const unsigned short* __restrict__ bufT_gp,
    const unsigned short* __restrict__ bufT_sp,
    const int* __restrict__ perm, const int* __restrict__ off_all,
    const float* __restrict__ W_gw, const float* __restrict__ b_gw,
    const float* __restrict__ W_sw, const float* __restrict__ b_sw,
    float* __restrict__ o_gw, float* __restrict__ o_sw,
    const float* __restrict__ R_pf,
    const float* __restrict__ bl_gp, const float* __restrict__ bl_sp,
    float* __restrict__ h_pf)
{
    const int b = blockIdx.x;
    const int tid = threadIdx.x;
    const int tx = tid & 31;
    const int g = tid >> 5;

    if (b < SEGP_BLKS) {
        // pfas: both segment means + finalize, one node per 32-lane group
        const int node = b * 16 + g;
        int loG = off_all[BASE_GP + node], hiG = off_all[BASE_GP + node + 1];
        h2_t tlG, thG;
        gather_sum_f16(bufT_gp, perm, loG, hiG, tx, tlG, thG);
        int loS = off_all[BASE_SP + node], hiS = off_all[BASE_SP + node + 1];
        h2_t tlS, thS;
        gather_sum_f16(bufT_sp, perm, loS, hiS, tx, tlS, thS);
        float invG = 1.0f / fmaxf((float)(hiG - loG), 1.0f);
        float invS = 1.0f / fmaxf((float)(hiS - loS), 1.0f);
        float4 rv = ((const float4*)R_pf)[(size_t)node * 32 + tx];
        float4 b1 = ((const float4*)bl_gp)[tx];
        float4 b2 = ((const float4*)bl_sp)[tx];
        float4 o;
        o.x = fmaxf(rv.x + (float)tlG.x * invG + (float)tlS.x * invS + b1.x + b2.x, 0.f);
        o.y = fmaxf(rv.y + (float)tlG.y * invG + (float)tlS.y * invS + b1.y + b2.y, 0.f);
        o.z = fmaxf(rv.z + (float)thG.x * invG + (float)thS.x * invS + b1.z + b2.z, 0.f);
        o.w = fmaxf(rv.w + (float)thG.y * invG + (float)thS.y * invS + b1.w + b2.w, 0.f);
        ((float4*)h_pf)[(size_t)node * 32 + tx] = o;
    } else {
        const int bb = b - SEGP_BLKS;
        int n; const _Float16* R; const float* bl; const unsigned short* bufT16;
        const int* off; const float* wout; const float* bout; float* out; int tile;
        if (bb < GW_BLKS) {
            n = N_GW; R = R_gw; bl = bl_pg; bufT16 = bufT_pg; off = off_all + BASE_PG;
            wout = W_gw; bout = b_gw; out = o_gw; tile = bb;
        } else {
            n = N_SW; R = R_sw; bl = bl_ps; bufT16 = bufT_ps; off = off_all + BASE_PS;
            wout = W_sw; bout = b_sw; out = o_sw; tile = bb - GW_BLKS;
        }
        const int rbase = tile * 32 + g * 2;
        float4 bv = ((const float4*)bl)[tx];
        float4 wo = ((const float4*)wout)[tx];
        float bo = bout[0];
#pragma unroll
        for (int rr = 0; rr < 2; ++rr) {
            int r = rbase + rr;
            int lo = 0, hi = 0;
            if (r < n) { lo = off[r]; hi = off[r + 1]; }
            h2_t tl, th;
            gather_sum_f16(bufT16, perm, lo, hi, tx, tl, th);
            float4 rf = make_float4(0.f, 0.f, 0.f, 0.f);
            if (r < n) {
                uint2 rv = *(const uint2*)((const unsigned short*)R + ((size_t)r << 7) + tx * 4);
                h2_t r01 = u2h2(rv.x), r23 = u2h2(rv.y);
                rf = make_float4((float)r01.x, (float)r01.y, (float)r23.x, (float)r23.y);
            }
            float inv = 1.0f / fmaxf((float)(hi - lo), 1.0f);
            float h0  = fmaxf(rf.x + bv.x + (float)tl.x * inv, 0.f);
            float h1  = fmaxf(rf.y + bv.y + (float)tl.y * inv, 0.f);
            float h2v = fmaxf(rf.z + bv.z + (float)th.x * inv, 0.f);
            float h3  = fmaxf(rf.w + bv.w + (float)th.y * inv, 0.f);
            float pv = h0 * wo.x + h1 * wo.y + h2v * wo.z + h3 * wo.w;
            pv += __shfl_xor(pv, 1, 32);
            pv += __shfl_xor(pv, 2, 32);
            pv += __shfl_xor(pv, 4, 32);
            pv += __shfl_xor(pv, 8, 32);
            pv += __shfl_xor(pv, 16, 32);
            if (tx == 0 && r < n) out[r] = pv + bo;
        }
    }
}

// ---------------------------------------------------------------------------
// Launch: 4 dispatches (prep -> trans_bin -> unbin -> gather).
// ---------------------------------------------------------------------------
extern "C" void kernel_launch(void* const* d_in, const int* in_sizes, int n_in,
                              void* d_out, int out_size, void* d_ws, size_t ws_size,
                              hipStream_t stream)
{
    const float* x_pfas = (const float*)d_in[0];
    const float* x_gw   = (const float*)d_in[1];
    const float* x_sw   = (const float*)d_in[2];
    const int* ei_pg_src = (const int*)d_in[3];
    const int* ei_pg_dst = (const int*)d_in[4];
    const int* ei_gp_src = (const int*)d_in[5];
    const int* ei_gp_dst = (const int*)d_in[6];
    const int* ei_ps_src = (const int*)d_in[7];
    const int* ei_ps_dst = (const int*)d_in[8];
    const int* ei_sp_src = (const int*)d_in[9];
    const int* ei_sp_dst = (const int*)d_in[10];
    const float* Wl_pg = (const float*)d_in[11];
    const float* bl_pg = (const float*)d_in[12];
    const float* Wr_pg = (const float*)d_in[13];
    const float* Wl_gp = (const float*)d_in[14];
    const float* bl_gp = (const float*)d_in[15];
    const float* Wr_gp = (const float*)d_in[16];
    const float* Wl_ps = (const float*)d_in[17];
    const float* bl_ps = (const float*)d_in[18];
    const float* Wr_ps = (const float*)d_in[19];
    const float* Wl_sp = (const float*)d_in[20];
    const float* bl_sp = (const float*)d_in[21];
    const float* Wr_sp = (const float*)d_in[22];
    const float* W_gw = (const float*)d_in[23];
    const float* b_gw = (const float*)d_in[24];
    const float* W_sw = (const float*)d_in[25];
    const float* b_sw = (const float*)d_in[26];

    float* out  = (float*)d_out;
    float* h_pf = out;                         // 20000*128
    float* o_gw = out + (size_t)N_PFAS * 128;  // 100000
    float* o_sw = o_gw + N_GW;                 // 30000

    // ---- workspace layout (~125 MB) ----
    char* p = (char*)d_ws;
    auto alloc = [&](size_t bytes) { char* q = p; p += (bytes + 15) & ~(size_t)15; return q; };
    unsigned short* bufT_pg = (unsigned short*)alloc((size_t)N_PFAS * 128 * 2);
    unsigned short* bufT_ps = (unsigned short*)alloc((size_t)N_PFAS * 128 * 2);
    unsigned short* bufT_gp = (unsigned short*)alloc((size_t)N_GW * 128 * 2);
    unsigned short* bufT_sp = (unsigned short*)alloc((size_t)N_SW * 128 * 2);
    _Float16* R_gw = (_Float16*)alloc((size_t)N_GW * 128 * 2);
    _Float16* R_sw = (_Float16*)alloc((size_t)N_SW * 128 * 2);
    float* R_pf = (float*)alloc((size_t)N_PFAS * 128 * 4);
    int* perm_all   = (int*)alloc((size_t)E_TOT * 4);
    unsigned* pairs = (unsigned*)alloc((size_t)NB * SEG_CAP * 4);   // 24.5 MB
    int* off_all    = (int*)alloc((size_t)(NTOT + 1) * 4);
    int* gcursor    = (int*)alloc((size_t)NB * 4);
    _Float16* WtF_pg  = (_Float16*)alloc(16384 * 2);
    _Float16* WtF_ps  = (_Float16*)alloc(16384 * 2);
    _Float16* WtFR_pf = (_Float16*)alloc(16384 * 2);
    _Float16* WtF_gp  = (_Float16*)alloc(16384 * 2);
    _Float16* WtFR_gw = (_Float16*)alloc(16384 * 2);
    _Float16* WtF_sp  = (_Float16*)alloc(16384 * 2);
    _Float16* WtFR_sw = (_Float16*)alloc(16384 * 2);

    // ---- 1. weight prep (+ gcursor zero, off_all[NTOT]) ----
    prep_wt_kernel<<<28, 256, 0, stream>>>(
        Wl_pg, Wl_ps, Wr_gp, Wr_sp, Wl_gp, Wr_pg, Wl_sp, Wr_ps,
        WtF_pg, WtF_ps, WtFR_pf, WtF_gp, WtFR_gw, WtF_sp, WtFR_sw,
        gcursor, off_all);

    // ---- 2. mega dispatch: LDS-staged MFMA products + edge binning ----
    trans_bin_kernel<<<BIN_NBLK + PROD_BLKS, 256, 0, stream>>>(
        x_pfas, x_gw, x_sw,
        WtF_pg, WtF_ps, WtFR_pf, WtF_gp, WtFR_gw, WtF_sp, WtFR_sw,
        (_Float16*)bufT_pg, (_Float16*)bufT_ps, R_pf,
        (_Float16*)bufT_gp, R_gw, (_Float16*)bufT_sp, R_sw,
        ei_pg_src, ei_pg_dst, ei_ps_src, ei_ps_dst,
        ei_gp_src, ei_gp_dst, ei_sp_src, ei_sp_dst,
        gcursor, pairs);

    // ---- 3. CSR finalize (self-prefixing unbin) ----
    unbin_kernel<<<NB, 512, 0, stream>>>(pairs, gcursor, off_all, perm_all);

    // ---- 4. merged gather: pfas (gp+sp+finalize) + gw/sw node passes ----
    gather_all_kernel<<<SEGP_BLKS + GW_BLKS + SW_BLKS, 512, 0, stream>>>(
        R_gw, R_sw, bl_pg, bl_ps, bufT_pg, bufT_ps, bufT_gp, bufT_sp,
        perm_all, off_all, W_gw, b_gw, W_sw, b_sw, o_gw, o_sw,
        R_pf, bl_gp, bl_sp, h_pf);
}